// Round 1
// baseline (3170.802 us; speedup 1.0000x reference)
//
#include <hip/hip_runtime.h>
#include <hip/hip_bf16.h>

#define NNODES 50000
#define NEDGES 800000
#define DF 128
#define KEXP 1280              // 10 planes * 128 (plane 9 = zero pad)
#define EPS 0.001f

typedef __bf16 bf16x8 __attribute__((ext_vector_type(8)));
typedef float  f32x4  __attribute__((ext_vector_type(4)));

// ---------------- weight pre-transform: Wt[o][k], k = c*128 + i ----------------
// c=0: base_w[o][i]; c=1..8: spline_w[o][i][c-1]; c=9: 0
__global__ void build_wt(const float* __restrict__ bw,
                         const float* __restrict__ sw,
                         __bf16* __restrict__ wt) {
    int gid = blockIdx.x * 256 + threadIdx.x;      // exactly DF*KEXP threads
    int o = gid / KEXP;
    int k = gid - o * KEXP;
    int c = k >> 7, i = k & 127;
    float v = 0.0f;
    if (c == 0)      v = bw[o * DF + i];
    else if (c <= 8) v = sw[(o * DF + i) * 8 + (c - 1)];
    wt[gid] = (__bf16)v;
}

// ---------------- degree / norm ----------------
__global__ void deg_count(const int* __restrict__ ei, int* __restrict__ deg) {
    int e = blockIdx.x * 256 + threadIdx.x;
    if (e >= NEDGES) return;
    atomicAdd(&deg[ei[NEDGES + e]], 1);
}

__global__ void compute_norm(const int* __restrict__ ei, const int* __restrict__ deg,
                             float* __restrict__ norm) {
    int e = blockIdx.x * 256 + threadIdx.x;
    if (e >= NEDGES) return;
    int s = ei[e];
    int d = ei[NEDGES + e];
    norm[e] = rsqrtf((float)(deg[s] + 1)) * rsqrtf((float)(deg[d] + 1));
}

// ---------------- scatter: agg[dst] += norm[e] * h[src]  (32 lanes/edge, float4) ----
__global__ void scatter_add(const int* __restrict__ ei, const float* __restrict__ norm,
                            const float* __restrict__ h, float* agg) {
    int tid = blockIdx.x * 256 + threadIdx.x;      // E*32 threads
    int e = tid >> 5;
    int l = tid & 31;
    if (e >= NEDGES) return;
    int s = ei[e];
    int d = ei[NEDGES + e];
    float w = norm[e];
    f32x4 v = *(const f32x4*)(h + (size_t)s * DF + l * 4);
    float* ap = agg + (size_t)d * DF + l * 4;
    unsafeAtomicAdd(ap + 0, w * v[0]);
    unsafeAtomicAdd(ap + 1, w * v[1]);
    unsafeAtomicAdd(ap + 2, w * v[2]);
    unsafeAtomicAdd(ap + 3, w * v[3]);
}

// ---------------- fused KAN transform (expansion + bf16 MFMA GEMM) ----------------
// mode 0: out = kan(hin)                       (write hl)
// mode 1: out = xadd + EPS*(hladd + kan(hin))  (Euler combine)
__global__ __launch_bounds__(256) void kan_gemm(
        const float* __restrict__ hin, const __bf16* __restrict__ wt,
        const float* xadd, const float* hladd, float* out, int mode) {
    __shared__ __bf16 Alds[128 * 40];   // [row][kk 0..31], row stride 40 (80B, 2-way ok)
    __shared__ __bf16 Blds[128 * 40];   // [o  ][kk 0..31]

    const int tid  = threadIdx.x;
    const int lane = tid & 63;
    const int wv   = tid >> 6;
    const int wRow = wv >> 1, wCol = wv & 1;
    const int n0   = blockIdx.x * 128;

    const int nloc = tid >> 1;          // expansion: row this thread fills
    const int half = tid & 1;           // which 8-wide i-half
    const int gRow = n0 + nloc;
    const int bo   = tid & 127;         // B staging: output column o
    const int bh   = tid >> 7;          // B staging: kk half (plane within pair)

    const int q  = lane >> 4;           // quad
    const int l15 = lane & 15;

    f32x4 acc[4][4] = {};

    float S[8], Wa[8], Wb[8], Wc[8], Wd[8];  // Wa=u^3/6(b=idx) .. Wd=(1-u)^3/6(b=idx-3)
    int IDX[8];

#pragma unroll 1
    for (int ic = 0; ic < 8; ++ic) {
        const int i0 = ic * 16;
        // ---- load 8 x values, compute basis cache once for all 9 planes ----
        float xv[8];
        if (gRow < NNODES) {
            f32x4 a = *(const f32x4*)(hin + (size_t)gRow * DF + i0 + half * 8);
            f32x4 b = *(const f32x4*)(hin + (size_t)gRow * DF + i0 + half * 8 + 4);
            xv[0]=a[0]; xv[1]=a[1]; xv[2]=a[2]; xv[3]=a[3];
            xv[4]=b[0]; xv[5]=b[1]; xv[6]=b[2]; xv[7]=b[3];
        } else {
#pragma unroll
            for (int j = 0; j < 8; ++j) xv[j] = 0.0f;
        }
#pragma unroll
        for (int j = 0; j < 8; ++j) {
            float x = xv[j];
            float f = (x + 2.2f) * 2.5f;       // (x - t0)/h, t0=-2.2, h=0.4
            float fi = floorf(f);
            IDX[j] = (int)fi;
            float u = f - fi;
            float u2 = u * u, u3 = u2 * u;
            float om = 1.0f - u;
            Wa[j] = u3 * (1.0f / 6.0f);
            Wb[j] = (((-3.0f * u + 3.0f) * u + 3.0f) * u + 1.0f) * (1.0f / 6.0f);
            Wc[j] = ((3.0f * u - 6.0f) * u2 + 4.0f) * (1.0f / 6.0f);
            Wd[j] = om * om * om * (1.0f / 6.0f);
            S[j]  = x / (1.0f + __expf(-x));   // silu
        }
        // ---- 5 plane-pair chunks: K=32 = {plane c0 (16 i), plane c1 (16 i)} ----
#pragma unroll
        for (int p = 0; p < 5; ++p) {
            const int c0 = 2 * p, c1 = c0 + 1;
            __syncthreads();                   // prev chunk's reads done
            bf16x8 av0, av1;
#pragma unroll
            for (int j = 0; j < 8; ++j) {
                float v0, v1;
                if (c0 == 0) v0 = S[j];
                else {
                    int t = IDX[j] - (c0 - 1);
                    v0 = (t==0)?Wa[j]:(t==1)?Wb[j]:(t==2)?Wc[j]:(t==3)?Wd[j]:0.0f;
                }
                if (c1 == 9) v1 = 0.0f;
                else {
                    int t = IDX[j] - (c1 - 1);
                    v1 = (t==0)?Wa[j]:(t==1)?Wb[j]:(t==2)?Wc[j]:(t==3)?Wd[j]:0.0f;
                }
                av0[j] = (__bf16)v0;
                av1[j] = (__bf16)v1;
            }
            *(bf16x8*)&Alds[nloc * 40 + half * 8]      = av0;  // kk = half*8+j   (c0)
            *(bf16x8*)&Alds[nloc * 40 + 16 + half * 8] = av1;  // kk = 16+half*8+j(c1)
            // stage B chunk: Blds[o][kk] = wt[o][ (c0+bh)*128 + i0 + (kk&15) ]
            {
                const uint4* wp = (const uint4*)(wt + (size_t)bo * KEXP + (c0 + bh) * DF + i0);
                uint4 w0 = wp[0], w1 = wp[1];
                *(uint4*)&Blds[bo * 40 + bh * 16]     = w0;
                *(uint4*)&Blds[bo * 40 + bh * 16 + 8] = w1;
            }
            __syncthreads();
            bf16x8 aF[4], bF[4];
#pragma unroll
            for (int mi = 0; mi < 4; ++mi)
                aF[mi] = *(const bf16x8*)&Alds[(wRow * 64 + mi * 16 + l15) * 40 + q * 8];
#pragma unroll
            for (int ni = 0; ni < 4; ++ni)
                bF[ni] = *(const bf16x8*)&Blds[(wCol * 64 + ni * 16 + l15) * 40 + q * 8];
#pragma unroll
            for (int mi = 0; mi < 4; ++mi)
#pragma unroll
                for (int ni = 0; ni < 4; ++ni)
                    acc[mi][ni] = __builtin_amdgcn_mfma_f32_16x16x32_bf16(
                        aF[mi], bF[ni], acc[mi][ni], 0, 0, 0);
        }
    }
    // ---- epilogue: D layout row = q*4+r, col = lane&15 (m89-verified) ----
#pragma unroll
    for (int mi = 0; mi < 4; ++mi) {
#pragma unroll
        for (int ni = 0; ni < 4; ++ni) {
#pragma unroll
            for (int r = 0; r < 4; ++r) {
                int row = n0 + wRow * 64 + mi * 16 + q * 4 + r;
                int col = wCol * 64 + ni * 16 + l15;
                if (row < NNODES) {
                    size_t idx = (size_t)row * DF + col;
                    float v = acc[mi][ni][r];
                    if (mode == 0) out[idx] = v;
                    else           out[idx] = xadd[idx] + EPS * (hladd[idx] + v);
                }
            }
        }
    }
}

extern "C" void kernel_launch(void* const* d_in, const int* in_sizes, int n_in,
                              void* d_out, int out_size, void* d_ws, size_t ws_size,
                              hipStream_t stream) {
    const float* x   = (const float*)d_in[0];
    const int*   ei  = (const int*)d_in[1];     // edge_index [2,E] int32
    const float* bwl = (const float*)d_in[2];
    const float* swl = (const float*)d_in[3];
    const float* bwc = (const float*)d_in[4];
    const float* swc = (const float*)d_in[5];
    float* out = (float*)d_out;

    char* ws = (char*)d_ws;
    float*  norm = (float*)(ws + 0);                 //  3,200,000 B
    int*    deg  = (int*)  (ws + 3200000);           //    200,000 B
    float*  agg  = (float*)(ws + 3400192);           // 25,600,000 B
    float*  hl   = (float*)(ws + 29000192);          // 25,600,000 B
    __bf16* wtl  = (__bf16*)(ws + 54600192);         //    327,680 B
    __bf16* wtc  = (__bf16*)(ws + 54927872);         //    327,680 B  (total ~52.7 MiB)

    build_wt<<<(DF * KEXP) / 256, 256, 0, stream>>>(bwl, swl, wtl);
    build_wt<<<(DF * KEXP) / 256, 256, 0, stream>>>(bwc, swc, wtc);

    hipMemsetAsync(deg, 0, NNODES * sizeof(int), stream);
    deg_count<<<(NEDGES + 255) / 256, 256, 0, stream>>>(ei, deg);
    compute_norm<<<(NEDGES + 255) / 256, 256, 0, stream>>>(ei, deg, norm);

    const int gemm_grid = (NNODES + 127) / 128;      // 391
    const float* h = x;
    for (int step = 0; step < 2; ++step) {           // delta_t = 2 (fixed by setup)
        hipMemsetAsync(agg, 0, (size_t)NNODES * DF * sizeof(float), stream);
        scatter_add<<<(NEDGES * 32) / 256, 256, 0, stream>>>(ei, norm, h, agg);
        kan_gemm<<<gemm_grid, 256, 0, stream>>>(h, wtl, nullptr, nullptr, hl, 0);
        kan_gemm<<<gemm_grid, 256, 0, stream>>>(agg, wtc, h, hl, out, 1);
        h = out;
    }
}

// Round 2
// 717.296 us; speedup vs baseline: 4.4205x; 4.4205x over previous
//
#include <hip/hip_runtime.h>
#include <hip/hip_bf16.h>

#define NNODES 50000
#define NEDGES 800000
#define DF 128
#define KEXP 1280              // 10 planes * 128 (plane 9 = zero pad)
#define EPS 0.001f

typedef __bf16 bf16x8 __attribute__((ext_vector_type(8)));
typedef float  f32x4  __attribute__((ext_vector_type(4)));

// ---------------- weight pre-transform: Wt[o][k], k = c*128 + i ----------------
__global__ void build_wt(const float* __restrict__ bw,
                         const float* __restrict__ sw,
                         __bf16* __restrict__ wt) {
    int gid = blockIdx.x * 256 + threadIdx.x;      // exactly DF*KEXP threads
    int o = gid / KEXP;
    int k = gid - o * KEXP;
    int c = k >> 7, i = k & 127;
    float v = 0.0f;
    if (c == 0)      v = bw[o * DF + i];
    else if (c <= 8) v = sw[(o * DF + i) * 8 + (c - 1)];
    wt[gid] = (__bf16)v;
}

// ---------------- CSR build ----------------
__global__ void deg_count(const int* __restrict__ ei, int* __restrict__ deg) {
    int e = blockIdx.x * 256 + threadIdx.x;
    if (e >= NEDGES) return;
    atomicAdd(&deg[ei[NEDGES + e]], 1);
}

// single-block exclusive scan of deg[0..N) -> rowptr[0..N]
__global__ __launch_bounds__(1024) void scan_rowptr(const int* __restrict__ deg,
                                                    int* __restrict__ rowptr) {
    __shared__ int buf[1024];
    __shared__ int carry;
    const int t = threadIdx.x;
    if (t == 0) carry = 0;
    __syncthreads();
    for (int base = 0; base < NNODES; base += 1024) {
        int i = base + t;
        int v = (i < NNODES) ? deg[i] : 0;
        buf[t] = v;
        __syncthreads();
        for (int off = 1; off < 1024; off <<= 1) {
            int x = (t >= off) ? buf[t - off] : 0;
            __syncthreads();
            buf[t] += x;
            __syncthreads();
        }
        int incl = buf[t];
        int c = carry;
        int total = buf[1023];
        __syncthreads();                 // everyone has read carry/buf
        if (i < NNODES) rowptr[i] = c + incl - v;
        if (t == 0) carry = c + total;
        __syncthreads();
    }
    if (threadIdx.x == 0) rowptr[NNODES] = carry;
}

// place each edge into its dst's CSR slot; norm computed inline
__global__ void fill_csr(const int* __restrict__ ei, const int* __restrict__ deg,
                         const int* __restrict__ rowptr, int* __restrict__ cnt,
                         int* __restrict__ esrc, float* __restrict__ ew) {
    int e = blockIdx.x * 256 + threadIdx.x;
    if (e >= NEDGES) return;
    int s = ei[e];
    int d = ei[NEDGES + e];
    float w = rsqrtf((float)(deg[s] + 1)) * rsqrtf((float)(deg[d] + 1));
    int p = rowptr[d] + atomicAdd(&cnt[d], 1);
    esrc[p] = s;
    ew[p] = w;
}

// ---------------- aggregation: one 32-lane half-wave per node, no atomics ----
__global__ __launch_bounds__(256) void agg_gather(
        const int* __restrict__ rowptr, const int* __restrict__ esrc,
        const float* __restrict__ ew, const float* __restrict__ h,
        float* __restrict__ agg) {
    const int tid = blockIdx.x * 256 + threadIdx.x;   // (N*32) threads
    const int n = tid >> 5;
    const int l = tid & 31;
    if (n >= NNODES) return;
    int p  = rowptr[n];
    const int pe = rowptr[n + 1];
    f32x4 acc = {0.0f, 0.0f, 0.0f, 0.0f};
    for (; p + 1 < pe; p += 2) {
        int   s0 = esrc[p],  s1 = esrc[p + 1];
        float w0 = ew[p],    w1 = ew[p + 1];
        f32x4 v0 = *(const f32x4*)(h + (size_t)s0 * DF + l * 4);
        f32x4 v1 = *(const f32x4*)(h + (size_t)s1 * DF + l * 4);
        acc[0] += w0 * v0[0]; acc[1] += w0 * v0[1];
        acc[2] += w0 * v0[2]; acc[3] += w0 * v0[3];
        acc[0] += w1 * v1[0]; acc[1] += w1 * v1[1];
        acc[2] += w1 * v1[2]; acc[3] += w1 * v1[3];
    }
    if (p < pe) {
        int   s0 = esrc[p];
        float w0 = ew[p];
        f32x4 v0 = *(const f32x4*)(h + (size_t)s0 * DF + l * 4);
        acc[0] += w0 * v0[0]; acc[1] += w0 * v0[1];
        acc[2] += w0 * v0[2]; acc[3] += w0 * v0[3];
    }
    *(f32x4*)(agg + (size_t)n * DF + l * 4) = acc;
}

// ---------------- fused KAN transform (expansion + bf16 MFMA GEMM) ----------------
// mode 0: out = kan(hin)                       (write hl)
// mode 1: out = xadd + EPS*(hladd + kan(hin))  (Euler combine)
__global__ __launch_bounds__(256) void kan_gemm(
        const float* __restrict__ hin, const __bf16* __restrict__ wt,
        const float* xadd, const float* hladd, float* out, int mode) {
    __shared__ __bf16 Alds[128 * 40];   // [row][kk 0..31], row stride 40 (80B, 2-way ok)
    __shared__ __bf16 Blds[128 * 40];   // [o  ][kk 0..31]

    const int tid  = threadIdx.x;
    const int lane = tid & 63;
    const int wv   = tid >> 6;
    const int wRow = wv >> 1, wCol = wv & 1;
    const int n0   = blockIdx.x * 128;

    const int nloc = tid >> 1;          // expansion: row this thread fills
    const int half = tid & 1;           // which 8-wide i-half
    const int gRow = n0 + nloc;
    const int bo   = tid & 127;         // B staging: output column o
    const int bh   = tid >> 7;          // B staging: kk half (plane within pair)

    const int q  = lane >> 4;           // quad
    const int l15 = lane & 15;

    f32x4 acc[4][4] = {};

    float S[8], Wa[8], Wb[8], Wc[8], Wd[8];
    int IDX[8];

#pragma unroll 1
    for (int ic = 0; ic < 8; ++ic) {
        const int i0 = ic * 16;
        float xv[8];
        if (gRow < NNODES) {
            f32x4 a = *(const f32x4*)(hin + (size_t)gRow * DF + i0 + half * 8);
            f32x4 b = *(const f32x4*)(hin + (size_t)gRow * DF + i0 + half * 8 + 4);
            xv[0]=a[0]; xv[1]=a[1]; xv[2]=a[2]; xv[3]=a[3];
            xv[4]=b[0]; xv[5]=b[1]; xv[6]=b[2]; xv[7]=b[3];
        } else {
#pragma unroll
            for (int j = 0; j < 8; ++j) xv[j] = 0.0f;
        }
#pragma unroll
        for (int j = 0; j < 8; ++j) {
            float x = xv[j];
            float f = (x + 2.2f) * 2.5f;       // (x - t0)/h, t0=-2.2, h=0.4
            float fi = floorf(f);
            IDX[j] = (int)fi;
            float u = f - fi;
            float u2 = u * u, u3 = u2 * u;
            float om = 1.0f - u;
            Wa[j] = u3 * (1.0f / 6.0f);
            Wb[j] = (((-3.0f * u + 3.0f) * u + 3.0f) * u + 1.0f) * (1.0f / 6.0f);
            Wc[j] = ((3.0f * u - 6.0f) * u2 + 4.0f) * (1.0f / 6.0f);
            Wd[j] = om * om * om * (1.0f / 6.0f);
            S[j]  = x / (1.0f + __expf(-x));   // silu
        }
#pragma unroll
        for (int p = 0; p < 5; ++p) {
            const int c0 = 2 * p, c1 = c0 + 1;
            __syncthreads();                   // prev chunk's reads done
            bf16x8 av0, av1;
#pragma unroll
            for (int j = 0; j < 8; ++j) {
                float v0, v1;
                if (c0 == 0) v0 = S[j];
                else {
                    int t = IDX[j] - (c0 - 1);
                    v0 = (t==0)?Wa[j]:(t==1)?Wb[j]:(t==2)?Wc[j]:(t==3)?Wd[j]:0.0f;
                }
                if (c1 == 9) v1 = 0.0f;
                else {
                    int t = IDX[j] - (c1 - 1);
                    v1 = (t==0)?Wa[j]:(t==1)?Wb[j]:(t==2)?Wc[j]:(t==3)?Wd[j]:0.0f;
                }
                av0[j] = (__bf16)v0;
                av1[j] = (__bf16)v1;
            }
            *(bf16x8*)&Alds[nloc * 40 + half * 8]      = av0;
            *(bf16x8*)&Alds[nloc * 40 + 16 + half * 8] = av1;
            {
                const uint4* wp = (const uint4*)(wt + (size_t)bo * KEXP + (c0 + bh) * DF + i0);
                uint4 w0 = wp[0], w1 = wp[1];
                *(uint4*)&Blds[bo * 40 + bh * 16]     = w0;
                *(uint4*)&Blds[bo * 40 + bh * 16 + 8] = w1;
            }
            __syncthreads();
            bf16x8 aF[4], bF[4];
#pragma unroll
            for (int mi = 0; mi < 4; ++mi)
                aF[mi] = *(const bf16x8*)&Alds[(wRow * 64 + mi * 16 + l15) * 40 + q * 8];
#pragma unroll
            for (int ni = 0; ni < 4; ++ni)
                bF[ni] = *(const bf16x8*)&Blds[(wCol * 64 + ni * 16 + l15) * 40 + q * 8];
#pragma unroll
            for (int mi = 0; mi < 4; ++mi)
#pragma unroll
                for (int ni = 0; ni < 4; ++ni)
                    acc[mi][ni] = __builtin_amdgcn_mfma_f32_16x16x32_bf16(
                        aF[mi], bF[ni], acc[mi][ni], 0, 0, 0);
        }
    }
#pragma unroll
    for (int mi = 0; mi < 4; ++mi) {
#pragma unroll
        for (int ni = 0; ni < 4; ++ni) {
#pragma unroll
            for (int r = 0; r < 4; ++r) {
                int row = n0 + wRow * 64 + mi * 16 + q * 4 + r;
                int col = wCol * 64 + ni * 16 + l15;
                if (row < NNODES) {
                    size_t idx = (size_t)row * DF + col;
                    float v = acc[mi][ni][r];
                    if (mode == 0) out[idx] = v;
                    else           out[idx] = xadd[idx] + EPS * (hladd[idx] + v);
                }
            }
        }
    }
}

extern "C" void kernel_launch(void* const* d_in, const int* in_sizes, int n_in,
                              void* d_out, int out_size, void* d_ws, size_t ws_size,
                              hipStream_t stream) {
    const float* x   = (const float*)d_in[0];
    const int*   ei  = (const int*)d_in[1];     // edge_index [2,E] int32
    const float* bwl = (const float*)d_in[2];
    const float* swl = (const float*)d_in[3];
    const float* bwc = (const float*)d_in[4];
    const float* swc = (const float*)d_in[5];
    float* out = (float*)d_out;

    char* ws = (char*)d_ws;
    int*    deg    = (int*)  (ws + 0);            //   200,000 B (pad 200,192)
    int*    cnt    = (int*)  (ws + 200192);       //   200,000 B (pad 200,128)
    int*    rowptr = (int*)  (ws + 400320);       //   200,004 B (pad 200,320)
    int*    esrc   = (int*)  (ws + 600640);       // 3,200,000 B
    float*  ew     = (float*)(ws + 3800640);      // 3,200,000 B
    float*  agg    = (float*)(ws + 7000640);      // 25,600,000 B
    float*  hl     = (float*)(ws + 32600640);     // 25,600,000 B
    __bf16* wtl    = (__bf16*)(ws + 58200640);    //   327,680 B
    __bf16* wtc    = (__bf16*)(ws + 58528320);    //   327,680 B  (total ~58.9 MB)

    build_wt<<<(DF * KEXP) / 256, 256, 0, stream>>>(bwl, swl, wtl);
    build_wt<<<(DF * KEXP) / 256, 256, 0, stream>>>(bwc, swc, wtc);

    hipMemsetAsync(deg, 0, NNODES * sizeof(int), stream);
    hipMemsetAsync(cnt, 0, NNODES * sizeof(int), stream);
    deg_count<<<(NEDGES + 255) / 256, 256, 0, stream>>>(ei, deg);
    scan_rowptr<<<1, 1024, 0, stream>>>(deg, rowptr);
    fill_csr<<<(NEDGES + 255) / 256, 256, 0, stream>>>(ei, deg, rowptr, cnt, esrc, ew);

    const int gemm_grid = (NNODES + 127) / 128;      // 391
    const float* h = x;
    for (int step = 0; step < 2; ++step) {           // delta_t = 2 (fixed by setup)
        agg_gather<<<(NNODES * 32 + 255) / 256, 256, 0, stream>>>(rowptr, esrc, ew, h, agg);
        kan_gemm<<<gemm_grid, 256, 0, stream>>>(h, wtl, nullptr, nullptr, hl, 0);
        kan_gemm<<<gemm_grid, 256, 0, stream>>>(agg, wtc, h, hl, out, 1);
        h = out;
    }
}